// Round 2
// baseline (545.587 us; speedup 1.0000x reference)
//
#include <hip/hip_runtime.h>
#include <math.h>

#define HH 2048
#define WW 2048
#define TT 11
constexpr long long HW = (long long)HH * WW;

struct MMat { float m[TT][TT]; };

// async global -> LDS copy, 16 B per lane. LDS dest is wave-uniform base
// (HW writes base + lane*16); global src is per-lane.
__device__ __forceinline__ void gload_lds16(const float* g, float* l)
{
    __builtin_amdgcn_global_load_lds(
        (const __attribute__((address_space(1))) unsigned int*)g,
        (__attribute__((address_space(3))) unsigned int*)l,
        16, 0, 0);
}

// ---------------- phy kernel ----------------
// R5 (resubmit): LDS row-sharing. Per block-slice stage 6 u-rows + 4 f1-rows
// (10 KB) into double-buffered LDS with async global_load_lds, instead of
// 12 u-row + 4 f1-row register loads. Cuts load-path traffic 738->461 MB and
// makes the global loads async: stage(s+1) is issued right after the barrier
// and only drains at the next barrier, so its latency hides behind slice s's
// ds_read+compute across the ~4 resident blocks/CU.
__global__ __launch_bounds__(256, 4) void phy_kernel(const float* __restrict__ u,
                                                     const float* __restrict__ f1,
                                                     MMat M,
                                                     float* __restrict__ ws)
{
    const int lane = threadIdx.x;              // 0..63
    const int ty   = threadIdx.y;              // 0..3 (= wave id)
    const int bx   = blockIdx.x;               // 0..8
    int w0 = bx * 252; if (w0 > WW - 256) w0 = WW - 256;   // aligned window start
    const int lo = bx * 252 + 1;               // first output col of this window
    int hi = bx * 252 + 252; if (hi > WW - 2) hi = WW - 2; // last output col

    const int h0 = 1 + blockIdx.y * 4;         // first output row of block
    const int h  = h0 + ty;                    // this thread's output row
    const float rowmask = (h <= HH - 2) ? 1.0f : 0.0f;

    const int col0 = w0 + lane * 4;            // absolute col of element .x
    float4 mask;
    {
        int c0 = col0, c1 = col0 + 1, c2 = col0 + 2, c3 = col0 + 3;
        mask.x = (c0 >= lo && c0 <= hi) ? rowmask : 0.0f;
        mask.y = (c1 >= lo && c1 <= hi) ? rowmask : 0.0f;
        mask.z = (c2 >= lo && c2 <= hi) ? rowmask : 0.0f;
        mask.w = (c3 >= lo && c3 <= hi) ? rowmask : 0.0f;
    }

    // staged global row indices (block-uniform; clamp keeps reads in bounds,
    // clamped rows only ever feed mask==0 outputs)
    int urow[6], frow[4];
    #pragma unroll
    for (int r = 0; r < 6; ++r) { int g = h0 - 1 + r; urow[r] = (g > HH - 1) ? (HH - 1) : g; }
    #pragma unroll
    for (int r = 0; r < 4; ++r) { int g = h0 + r;     frow[r] = (g > HH - 1) ? (HH - 1) : g; }

    // LDS: 2 buffers x (6 u-rows + 4 f1-rows) x 256 cols
    __shared__ float lds[2][10 * 256];

    const float c0f = 0.34520446044393f;
    const float c1f = 0.309591078922457f;
    const float c2f = -2.619182157203629f;
    const float kod = 0.01f * 4194304.0f;   // KAPPA / DX^2

    float4 D[TT];
    #pragma unroll
    for (int t = 0; t < TT; ++t) D[t] = make_float4(0.f, 0.f, 0.f, 0.f);

    float acc = 0.0f;

    // one async row-stage: rows 0..5 = u rows, rows 6..9 = f1 rows
    auto stageRow = [&](int s, int b, int r) {
        const float* base = (r < 6)
            ? (u  + (long long)s * HW + (long long)urow[r]     * WW)
            : (f1 + (long long)s * HW + (long long)frow[r - 6] * WW);
        gload_lds16(base + w0 + lane * 4, &lds[b][r * 256]);
    };
    auto stage = [&](int s, int b) {
        stageRow(s, b, ty);           // rows 0..3
        stageRow(s, b, ty + 4);       // rows 4..7
        if (ty < 2) stageRow(s, b, ty + 8);  // rows 8..9 (wave-uniform branch)
    };

    // prologue: slice 0 staging in flight
    stage(0, 0);

    #pragma unroll
    for (int s = 0; s < TT; ++s) {
        // drains this wave's outstanding stage (vmcnt 0) + block-wide sync:
        // after this, buf[s&1] is fully staged and visible.
        __syncthreads();

        // issue next slice's staging into the other buffer; it drains at the
        // NEXT barrier, so its latency overlaps this slice's compute.
        if (s + 1 < TT) stage(s + 1, (s + 1) & 1);

        const float* Lb = &lds[s & 1][0];
        const float4 vm = *(const float4*)&Lb[(ty    ) * 256 + lane * 4];
        const float4 v0 = *(const float4*)&Lb[(ty + 1) * 256 + lane * 4];
        const float4 vp = *(const float4*)&Lb[(ty + 2) * 256 + lane * 4];
        const float4 fv = *(const float4*)&Lb[(6 + ty) * 256 + lane * 4];

        // in-wave horizontal neighbors (window pos 0 / 255 never output -> garbage safe)
        const float lm = __shfl_up(vm.w, 1);
        const float l0 = __shfl_up(v0.w, 1);
        const float lp = __shfl_up(vp.w, 1);
        const float rm = __shfl_down(vm.x, 1);
        const float r0 = __shfl_down(v0.x, 1);
        const float rp = __shfl_down(vp.x, 1);

        float4 lap;
        lap.x = c0f * ((lm   + vm.y) + (lp   + vp.y)) + c1f * ((vm.x + vp.x) + (l0   + v0.y)) + c2f * v0.x;
        lap.y = c0f * ((vm.x + vm.z) + (vp.x + vp.z)) + c1f * ((vm.y + vp.y) + (v0.x + v0.z)) + c2f * v0.y;
        lap.z = c0f * ((vm.y + vm.w) + (vp.y + vp.w)) + c1f * ((vm.z + vp.z) + (v0.y + v0.w)) + c2f * v0.z;
        lap.w = c0f * ((vm.z + rm  ) + (vp.z + rp  )) + c1f * ((vm.w + vp.w) + (v0.z + r0  )) + c2f * v0.w;

        // fu[s] = D[s] (partials s'<s) + M[s][s]*u_s + (u_s - kod*lap - f1)
        const float mss = M.m[s][s];
        float fx = (D[s].x + mss * v0.x + (v0.x - kod * lap.x - fv.x)) * mask.x;
        float fy = (D[s].y + mss * v0.y + (v0.y - kod * lap.y - fv.y)) * mask.y;
        float fz = (D[s].z + mss * v0.z + (v0.z - kod * lap.z - fv.z)) * mask.z;
        float fw = (D[s].w + mss * v0.w + (v0.w - kod * lap.w - fv.w)) * mask.w;
        acc += fx * fx + fy * fy + fz * fz + fw * fw;

        #pragma unroll
        for (int t = s + 1; t < TT; ++t) {
            const float m = M.m[t][s];
            D[t].x += m * v0.x;
            D[t].y += m * v0.y;
            D[t].z += m * v0.z;
            D[t].w += m * v0.w;
        }
    }

    // 3-level reduction: wave shuffle -> LDS -> one atomic per block
    #pragma unroll
    for (int off = 32; off > 0; off >>= 1)
        acc += __shfl_down(acc, off, 64);
    __shared__ float wsum[4];
    const int tid = ty * 64 + lane;
    const int wid = tid >> 6;
    if (lane == 0) wsum[wid] = acc;
    __syncthreads();
    if (tid == 0) {
        float s = (wsum[0] + wsum[1]) + (wsum[2] + wsum[3]);
        atomicAdd(&ws[0], s);
    }
}

// ---------------- bc kernel: boundary loss ----------------
__global__ __launch_bounds__(256) void bc_kernel(const float* __restrict__ u,
                                                 float* __restrict__ ws)
{
    int idx = blockIdx.x * 256 + threadIdx.x;   // 0 .. 10*2048-1
    float acc = 0.0f;
    if (idx < 10 * 2048) {
        int i = idx >> 11;       // time index 0..9 (u slice i+1)
        int j = idx & 2047;
        float tval = 0.1f + 0.1f * (float)i;
        float xj = (float)j * (1.0f / 2047.0f);
        float x1 = powf(tval, 1.5f) * sinf(6.283185307179586f * xj);
        const float* ub = u + (long long)(i + 1) * HW;
        float l = ub[(long long)j * WW + 0]        - x1;
        float r = ub[(long long)j * WW + (WW - 1)] - x1;
        float tp = ub[j]                            - x1;
        float bt = ub[(long long)(HH - 1) * WW + j] - x1;
        acc = l * l + r * r + tp * tp + bt * bt;
    }
    #pragma unroll
    for (int off = 32; off > 0; off >>= 1)
        acc += __shfl_down(acc, off, 64);
    __shared__ float wsum[4];
    int tid = threadIdx.x;
    int lane = tid & 63, wid = tid >> 6;
    if (lane == 0) wsum[wid] = acc;
    __syncthreads();
    if (tid == 0) {
        float s = (wsum[0] + wsum[1]) + (wsum[2] + wsum[3]);
        atomicAdd(&ws[1], s);
    }
}

// ---------------- finalize ----------------
__global__ void fin_kernel(const float* __restrict__ ws, float* __restrict__ out)
{
    out[0] = ws[0] * (2.0f / (11.0f * 2046.0f * 2046.0f));
    out[1] = ws[1] * (1.0f / (10.0f * 2048.0f * 2048.0f));
}

static MMat make_M()
{
    double w[10];
    w[0] = 1.0;
    for (int j = 1; j <= 9; ++j)
        w[j] = pow((double)j + 1.0, 0.5) - pow((double)j, 0.5);
    double M[TT][TT] = {};
    for (int i = 1; i < TT; ++i) {
        M[i][i] = w[0];
        M[i][0] -= w[i - 1];
        for (int k = 1; k < i; ++k)
            M[i][k] = -(w[i - k - 1] - w[i - k]);
    }
    double pref = pow(0.1, -0.5) / 0.886226925452758;
    MMat r;
    for (int i = 0; i < TT; ++i)
        for (int j = 0; j < TT; ++j)
            r.m[i][j] = (float)(pref * M[i][j]);
    return r;
}

extern "C" void kernel_launch(void* const* d_in, const int* in_sizes, int n_in,
                              void* d_out, int out_size, void* d_ws, size_t ws_size,
                              hipStream_t stream)
{
    const float* u  = (const float*)d_in[0];
    const float* f1 = (const float*)d_in[1];
    float* out = (float*)d_out;
    float* ws  = (float*)d_ws;

    MMat M = make_M();

    hipMemsetAsync(ws, 0, 2 * sizeof(float), stream);

    dim3 block(64, 4);
    dim3 grid(9, 512);   // 9 col-windows (252 output cols each), 512*4 = 2048 rows
    phy_kernel<<<grid, block, 0, stream>>>(u, f1, M, ws);

    bc_kernel<<<(10 * 2048 + 255) / 256, 256, 0, stream>>>(u, ws);

    fin_kernel<<<1, 1, 0, stream>>>(ws, out);
}

// Round 3
// 371.213 us; speedup vs baseline: 1.4697x; 1.4697x over previous
//
#include <hip/hip_runtime.h>
#include <math.h>

#define HH 2048
#define WW 2048
#define TT 11
constexpr long long HW = (long long)HH * WW;

struct MMat { float m[TT][TT]; };

__device__ __forceinline__ float4 ld4(const float* p) { return *(const float4*)p; }

// ---------------- phy kernel ----------------
// R6: revert to the proven R4 register structure (127 us) and deepen the
// software pipeline from 2-deep to 3-deep: slice s+2's four float4 loads are
// issued while slice s is consumed, so each wave keeps ~8 load instructions
// in flight (vmcnt(8) at consume) instead of 4. Attacks the latency/queueing
// bound (VALU 23%, HBM 27%, both far from ceiling => outstanding-request
// limited). Rotating 3-slot register buffers with static (s%3) indices inside
// the fully-unrolled TT loop -- no lambdas, no runtime-indexed arrays
// (R5 post-mortem: lambda-captured arrays sent D[] to scratch, 530 MB of
// HBM write traffic; tripwire is WRITE_SIZE >> 144 KB).
__global__ __launch_bounds__(256, 4) void phy_kernel(const float* __restrict__ u,
                                                     const float* __restrict__ f1,
                                                     MMat M,
                                                     float* __restrict__ ws)
{
    const int lane = threadIdx.x;              // 0..63
    const int ty   = threadIdx.y;              // 0..3
    const int bx   = blockIdx.x;               // 0..8
    int w0 = bx * 252; if (w0 > WW - 256) w0 = WW - 256;   // aligned window start
    const int lo = bx * 252 + 1;               // first output col of this window
    int hi = bx * 252 + 252; if (hi > WW - 2) hi = WW - 2; // last output col

    const int h    = 1 + blockIdx.y * 4 + ty;  // 1..2048
    const int heff = (h > HH - 2) ? (HH - 2) : h;
    const float rowmask = (h <= HH - 2) ? 1.0f : 0.0f;

    const int col0 = w0 + lane * 4;            // absolute col of element .x
    float4 mask;
    {
        int c0 = col0, c1 = col0 + 1, c2 = col0 + 2, c3 = col0 + 3;
        mask.x = (c0 >= lo && c0 <= hi) ? rowmask : 0.0f;
        mask.y = (c1 >= lo && c1 <= hi) ? rowmask : 0.0f;
        mask.z = (c2 >= lo && c2 <= hi) ? rowmask : 0.0f;
        mask.w = (c3 >= lo && c3 <= hi) ? rowmask : 0.0f;
    }

    const long long rowm = (long long)(heff - 1) * WW + col0;
    const long long row0 = (long long)heff * WW + col0;
    const long long rowp = (long long)(heff + 1) * WW + col0;

    const float c0f = 0.34520446044393f;
    const float c1f = 0.309591078922457f;
    const float c2f = -2.619182157203629f;
    const float kod = 0.01f * 4194304.0f;   // KAPPA / DX^2

    float4 D[TT];
    #pragma unroll
    for (int t = 0; t < TT; ++t) D[t] = make_float4(0.f, 0.f, 0.f, 0.f);

    float acc = 0.0f;

    // 3-slot rotating load buffers (indices are compile-time after unroll)
    float4 vmB[3], v0B[3], vpB[3], fvB[3];

    // pipeline prologue: slices 0 and 1 in flight
    {
        const float* us0 = u;
        vmB[0] = ld4(us0 + rowm);
        v0B[0] = ld4(us0 + row0);
        vpB[0] = ld4(us0 + rowp);
        fvB[0] = ld4(f1 + row0);
        const float* us1 = u + HW;
        vmB[1] = ld4(us1 + rowm);
        v0B[1] = ld4(us1 + row0);
        vpB[1] = ld4(us1 + rowp);
        fvB[1] = ld4(f1 + HW + row0);
    }

    #pragma unroll
    for (int s = 0; s < TT; ++s) {
        const int cs = s % 3;

        // issue slice s+2's loads BEFORE consuming slice s (2-ahead prefetch)
        if (s + 2 < TT) {
            const int ns = (s + 2) % 3;
            const float* un = u + (long long)(s + 2) * HW;
            vmB[ns] = ld4(un + rowm);
            v0B[ns] = ld4(un + row0);
            vpB[ns] = ld4(un + rowp);
            fvB[ns] = ld4(f1 + (long long)(s + 2) * HW + row0);
        }

        const float4 vm = vmB[cs];
        const float4 v0 = v0B[cs];
        const float4 vp = vpB[cs];
        const float4 fv = fvB[cs];

        // in-wave horizontal neighbors (window pos 0 / 255 never output -> garbage safe)
        const float lm = __shfl_up(vm.w, 1);
        const float l0 = __shfl_up(v0.w, 1);
        const float lp = __shfl_up(vp.w, 1);
        const float rm = __shfl_down(vm.x, 1);
        const float r0 = __shfl_down(v0.x, 1);
        const float rp = __shfl_down(vp.x, 1);

        float4 lap;
        lap.x = c0f * ((lm   + vm.y) + (lp   + vp.y)) + c1f * ((vm.x + vp.x) + (l0   + v0.y)) + c2f * v0.x;
        lap.y = c0f * ((vm.x + vm.z) + (vp.x + vp.z)) + c1f * ((vm.y + vp.y) + (v0.x + v0.z)) + c2f * v0.y;
        lap.z = c0f * ((vm.y + vm.w) + (vp.y + vp.w)) + c1f * ((vm.z + vp.z) + (v0.y + v0.w)) + c2f * v0.z;
        lap.w = c0f * ((vm.z + rm  ) + (vp.z + rp  )) + c1f * ((vm.w + vp.w) + (v0.z + r0  )) + c2f * v0.w;

        // fu[s] = D[s] (partials s'<s) + M[s][s]*u_s + (u_s - kod*lap - f1)
        const float mss = M.m[s][s];
        float fx = (D[s].x + mss * v0.x + (v0.x - kod * lap.x - fv.x)) * mask.x;
        float fy = (D[s].y + mss * v0.y + (v0.y - kod * lap.y - fv.y)) * mask.y;
        float fz = (D[s].z + mss * v0.z + (v0.z - kod * lap.z - fv.z)) * mask.z;
        float fw = (D[s].w + mss * v0.w + (v0.w - kod * lap.w - fv.w)) * mask.w;
        acc += fx * fx + fy * fy + fz * fz + fw * fw;

        #pragma unroll
        for (int t = s + 1; t < TT; ++t) {
            const float m = M.m[t][s];
            D[t].x += m * v0.x;
            D[t].y += m * v0.y;
            D[t].z += m * v0.z;
            D[t].w += m * v0.w;
        }
    }

    // 3-level reduction: wave shuffle -> LDS -> one atomic per block
    #pragma unroll
    for (int off = 32; off > 0; off >>= 1)
        acc += __shfl_down(acc, off, 64);
    __shared__ float wsum[4];
    const int tid = ty * 64 + lane;
    const int wid = tid >> 6;
    if (lane == 0) wsum[wid] = acc;
    __syncthreads();
    if (tid == 0) {
        float s = (wsum[0] + wsum[1]) + (wsum[2] + wsum[3]);
        atomicAdd(&ws[0], s);
    }
}

// ---------------- bc kernel: boundary loss ----------------
__global__ __launch_bounds__(256) void bc_kernel(const float* __restrict__ u,
                                                 float* __restrict__ ws)
{
    int idx = blockIdx.x * 256 + threadIdx.x;   // 0 .. 10*2048-1
    float acc = 0.0f;
    if (idx < 10 * 2048) {
        int i = idx >> 11;       // time index 0..9 (u slice i+1)
        int j = idx & 2047;
        float tval = 0.1f + 0.1f * (float)i;
        float xj = (float)j * (1.0f / 2047.0f);
        float x1 = powf(tval, 1.5f) * sinf(6.283185307179586f * xj);
        const float* ub = u + (long long)(i + 1) * HW;
        float l = ub[(long long)j * WW + 0]        - x1;
        float r = ub[(long long)j * WW + (WW - 1)] - x1;
        float tp = ub[j]                            - x1;
        float bt = ub[(long long)(HH - 1) * WW + j] - x1;
        acc = l * l + r * r + tp * tp + bt * bt;
    }
    #pragma unroll
    for (int off = 32; off > 0; off >>= 1)
        acc += __shfl_down(acc, off, 64);
    __shared__ float wsum[4];
    int tid = threadIdx.x;
    int lane = tid & 63, wid = tid >> 6;
    if (lane == 0) wsum[wid] = acc;
    __syncthreads();
    if (tid == 0) {
        float s = (wsum[0] + wsum[1]) + (wsum[2] + wsum[3]);
        atomicAdd(&ws[1], s);
    }
}

// ---------------- finalize ----------------
__global__ void fin_kernel(const float* __restrict__ ws, float* __restrict__ out)
{
    out[0] = ws[0] * (2.0f / (11.0f * 2046.0f * 2046.0f));
    out[1] = ws[1] * (1.0f / (10.0f * 2048.0f * 2048.0f));
}

static MMat make_M()
{
    double w[10];
    w[0] = 1.0;
    for (int j = 1; j <= 9; ++j)
        w[j] = pow((double)j + 1.0, 0.5) - pow((double)j, 0.5);
    double M[TT][TT] = {};
    for (int i = 1; i < TT; ++i) {
        M[i][i] = w[0];
        M[i][0] -= w[i - 1];
        for (int k = 1; k < i; ++k)
            M[i][k] = -(w[i - k - 1] - w[i - k]);
    }
    double pref = pow(0.1, -0.5) / 0.886226925452758;
    MMat r;
    for (int i = 0; i < TT; ++i)
        for (int j = 0; j < TT; ++j)
            r.m[i][j] = (float)(pref * M[i][j]);
    return r;
}

extern "C" void kernel_launch(void* const* d_in, const int* in_sizes, int n_in,
                              void* d_out, int out_size, void* d_ws, size_t ws_size,
                              hipStream_t stream)
{
    const float* u  = (const float*)d_in[0];
    const float* f1 = (const float*)d_in[1];
    float* out = (float*)d_out;
    float* ws  = (float*)d_ws;

    MMat M = make_M();

    hipMemsetAsync(ws, 0, 2 * sizeof(float), stream);

    dim3 block(64, 4);
    dim3 grid(9, 512);   // 9 col-windows (252 output cols each), 512*4 = 2048 rows
    phy_kernel<<<grid, block, 0, stream>>>(u, f1, M, ws);

    bc_kernel<<<(10 * 2048 + 255) / 256, 256, 0, stream>>>(u, ws);

    fin_kernel<<<1, 1, 0, stream>>>(ws, out);
}

// Round 4
// 367.729 us; speedup vs baseline: 1.4837x; 1.0095x over previous
//
#include <hip/hip_runtime.h>
#include <math.h>

#define HH 2048
#define WW 2048
#define TT 11
constexpr long long HW = (long long)HH * WW;

struct MMat { float m[TT][TT]; };

__device__ __forceinline__ float4 ld4(const float* p) { return *(const float4*)p; }

// ---------------- phy kernel ----------------
// R7: 2 output rows per thread. Theory: dur == VMEM_bytes / ~6.4 TB/s
// (R4/R6: 811 MB / 126 us = 6.45 TB/s = float4 streaming ceiling, while HBM
// sits at 27% and VALU at 23%). So the lever is VMEM bytes. Each thread now
// loads 4 u-rows + 2 f1-rows per slice for 2 output rows (3 KB/row vs 4),
// cutting traffic 811 -> 622 MB. D[] doubles to 88 VGPR -> launch_bounds
// (256,3) (cap 170) so a scratch spill is impossible (R5 lesson: WRITE_SIZE
// is the tripwire, must stay ~144 KB).
__global__ __launch_bounds__(256, 3) void phy_kernel(const float* __restrict__ u,
                                                     const float* __restrict__ f1,
                                                     MMat M,
                                                     float* __restrict__ ws)
{
    const int lane = threadIdx.x;              // 0..63
    const int ty   = threadIdx.y;              // 0..3
    const int bx   = blockIdx.x;               // 0..8
    int w0 = bx * 252; if (w0 > WW - 256) w0 = WW - 256;   // aligned window start
    const int lo = bx * 252 + 1;               // first output col of this window
    int hi = bx * 252 + 252; if (hi > WW - 2) hi = WW - 2; // last output col

    const int h = 1 + blockIdx.y * 8 + ty * 2; // first of this thread's 2 rows (1..2047)
    // loaded rows h-1..h+2, clamped in-bounds; clamped rows only feed masked outputs
    const int lr0 = h - 1;
    const int lr1 = h;
    const int lr2 = (h + 1 > HH - 1) ? (HH - 1) : (h + 1);
    const int lr3 = (h + 2 > HH - 1) ? (HH - 1) : (h + 2);
    const float rm0 = (h     <= HH - 2) ? 1.0f : 0.0f;
    const float rm1 = (h + 1 <= HH - 2) ? 1.0f : 0.0f;

    const int col0 = w0 + lane * 4;            // absolute col of element .x
    float4 cmask;
    {
        int c0 = col0, c1 = col0 + 1, c2 = col0 + 2, c3 = col0 + 3;
        cmask.x = (c0 >= lo && c0 <= hi) ? 1.0f : 0.0f;
        cmask.y = (c1 >= lo && c1 <= hi) ? 1.0f : 0.0f;
        cmask.z = (c2 >= lo && c2 <= hi) ? 1.0f : 0.0f;
        cmask.w = (c3 >= lo && c3 <= hi) ? 1.0f : 0.0f;
    }
    float4 mA = make_float4(cmask.x * rm0, cmask.y * rm0, cmask.z * rm0, cmask.w * rm0);
    float4 mB = make_float4(cmask.x * rm1, cmask.y * rm1, cmask.z * rm1, cmask.w * rm1);

    const long long o0 = (long long)lr0 * WW + col0;
    const long long o1 = (long long)lr1 * WW + col0;
    const long long o2 = (long long)lr2 * WW + col0;
    const long long o3 = (long long)lr3 * WW + col0;

    const float c0f = 0.34520446044393f;
    const float c1f = 0.309591078922457f;
    const float c2f = -2.619182157203629f;
    const float kod = 0.01f * 4194304.0f;   // KAPPA / DX^2

    float4 D0[TT], D1[TT];
    #pragma unroll
    for (int t = 0; t < TT; ++t) {
        D0[t] = make_float4(0.f, 0.f, 0.f, 0.f);
        D1[t] = make_float4(0.f, 0.f, 0.f, 0.f);
    }

    float acc = 0.0f;

    // 2-deep pipeline (R4 proven shape): slice 0 loads in flight
    float4 a_n = ld4(u + o0);
    float4 b_n = ld4(u + o1);
    float4 c_n = ld4(u + o2);
    float4 d_n = ld4(u + o3);
    float4 f_n = ld4(f1 + o1);
    float4 g_n = ld4(f1 + o2);

    #pragma unroll
    for (int s = 0; s < TT; ++s) {
        const float4 a = a_n;   // u row h-1
        const float4 b = b_n;   // u row h
        const float4 c = c_n;   // u row h+1
        const float4 d = d_n;   // u row h+2
        const float4 f = f_n;   // f1 row h
        const float4 g = g_n;   // f1 row h+1

        if (s + 1 < TT) {
            const float* un = u  + (long long)(s + 1) * HW;
            const float* fn = f1 + (long long)(s + 1) * HW;
            a_n = ld4(un + o0);
            b_n = ld4(un + o1);
            c_n = ld4(un + o2);
            d_n = ld4(un + o3);
            f_n = ld4(fn + o1);
            g_n = ld4(fn + o2);
        }

        // in-wave horizontal neighbors (window pos 0 / 255 never output -> garbage safe)
        const float la = __shfl_up(a.w, 1);
        const float lb = __shfl_up(b.w, 1);
        const float lc = __shfl_up(c.w, 1);
        const float ld_ = __shfl_up(d.w, 1);
        const float ra = __shfl_down(a.x, 1);
        const float rb = __shfl_down(b.x, 1);
        const float rc = __shfl_down(c.x, 1);
        const float rd = __shfl_down(d.x, 1);

        // lap for row h: vm=a, v0=b, vp=c
        float4 lap0;
        lap0.x = c0f * ((la  + a.y) + (lc  + c.y)) + c1f * ((a.x + c.x) + (lb  + b.y)) + c2f * b.x;
        lap0.y = c0f * ((a.x + a.z) + (c.x + c.z)) + c1f * ((a.y + c.y) + (b.x + b.z)) + c2f * b.y;
        lap0.z = c0f * ((a.y + a.w) + (c.y + c.w)) + c1f * ((a.z + c.z) + (b.y + b.w)) + c2f * b.z;
        lap0.w = c0f * ((a.z + ra ) + (c.z + rc )) + c1f * ((a.w + c.w) + (b.z + rb )) + c2f * b.w;

        // lap for row h+1: vm=b, v0=c, vp=d
        float4 lap1;
        lap1.x = c0f * ((lb  + b.y) + (ld_ + d.y)) + c1f * ((b.x + d.x) + (lc  + c.y)) + c2f * c.x;
        lap1.y = c0f * ((b.x + b.z) + (d.x + d.z)) + c1f * ((b.y + d.y) + (c.x + c.z)) + c2f * c.y;
        lap1.z = c0f * ((b.y + b.w) + (d.y + d.w)) + c1f * ((b.z + d.z) + (c.y + c.w)) + c2f * c.z;
        lap1.w = c0f * ((b.z + rb ) + (d.z + rd )) + c1f * ((b.w + d.w) + (c.z + rc )) + c2f * c.w;

        // fu = D (partials s'<s) + M[s][s]*u_s + (u_s - kod*lap - f1)
        const float mss = M.m[s][s];
        float fx0 = (D0[s].x + mss * b.x + (b.x - kod * lap0.x - f.x)) * mA.x;
        float fy0 = (D0[s].y + mss * b.y + (b.y - kod * lap0.y - f.y)) * mA.y;
        float fz0 = (D0[s].z + mss * b.z + (b.z - kod * lap0.z - f.z)) * mA.z;
        float fw0 = (D0[s].w + mss * b.w + (b.w - kod * lap0.w - f.w)) * mA.w;
        acc += fx0 * fx0 + fy0 * fy0 + fz0 * fz0 + fw0 * fw0;

        float fx1 = (D1[s].x + mss * c.x + (c.x - kod * lap1.x - g.x)) * mB.x;
        float fy1 = (D1[s].y + mss * c.y + (c.y - kod * lap1.y - g.y)) * mB.y;
        float fz1 = (D1[s].z + mss * c.z + (c.z - kod * lap1.z - g.z)) * mB.z;
        float fw1 = (D1[s].w + mss * c.w + (c.w - kod * lap1.w - g.w)) * mB.w;
        acc += fx1 * fx1 + fy1 * fy1 + fz1 * fz1 + fw1 * fw1;

        #pragma unroll
        for (int t = s + 1; t < TT; ++t) {
            const float m = M.m[t][s];
            D0[t].x += m * b.x;
            D0[t].y += m * b.y;
            D0[t].z += m * b.z;
            D0[t].w += m * b.w;
            D1[t].x += m * c.x;
            D1[t].y += m * c.y;
            D1[t].z += m * c.z;
            D1[t].w += m * c.w;
        }
    }

    // 3-level reduction: wave shuffle -> LDS -> one atomic per block
    #pragma unroll
    for (int off = 32; off > 0; off >>= 1)
        acc += __shfl_down(acc, off, 64);
    __shared__ float wsum[4];
    const int tid = ty * 64 + lane;
    const int wid = tid >> 6;
    if (lane == 0) wsum[wid] = acc;
    __syncthreads();
    if (tid == 0) {
        float s = (wsum[0] + wsum[1]) + (wsum[2] + wsum[3]);
        atomicAdd(&ws[0], s);
    }
}

// ---------------- bc kernel: boundary loss ----------------
__global__ __launch_bounds__(256) void bc_kernel(const float* __restrict__ u,
                                                 float* __restrict__ ws)
{
    int idx = blockIdx.x * 256 + threadIdx.x;   // 0 .. 10*2048-1
    float acc = 0.0f;
    if (idx < 10 * 2048) {
        int i = idx >> 11;       // time index 0..9 (u slice i+1)
        int j = idx & 2047;
        float tval = 0.1f + 0.1f * (float)i;
        float xj = (float)j * (1.0f / 2047.0f);
        float x1 = powf(tval, 1.5f) * sinf(6.283185307179586f * xj);
        const float* ub = u + (long long)(i + 1) * HW;
        float l = ub[(long long)j * WW + 0]        - x1;
        float r = ub[(long long)j * WW + (WW - 1)] - x1;
        float tp = ub[j]                            - x1;
        float bt = ub[(long long)(HH - 1) * WW + j] - x1;
        acc = l * l + r * r + tp * tp + bt * bt;
    }
    #pragma unroll
    for (int off = 32; off > 0; off >>= 1)
        acc += __shfl_down(acc, off, 64);
    __shared__ float wsum[4];
    int tid = threadIdx.x;
    int lane = tid & 63, wid = tid >> 6;
    if (lane == 0) wsum[wid] = acc;
    __syncthreads();
    if (tid == 0) {
        float s = (wsum[0] + wsum[1]) + (wsum[2] + wsum[3]);
        atomicAdd(&ws[1], s);
    }
}

// ---------------- finalize ----------------
__global__ void fin_kernel(const float* __restrict__ ws, float* __restrict__ out)
{
    out[0] = ws[0] * (2.0f / (11.0f * 2046.0f * 2046.0f));
    out[1] = ws[1] * (1.0f / (10.0f * 2048.0f * 2048.0f));
}

static MMat make_M()
{
    double w[10];
    w[0] = 1.0;
    for (int j = 1; j <= 9; ++j)
        w[j] = pow((double)j + 1.0, 0.5) - pow((double)j, 0.5);
    double M[TT][TT] = {};
    for (int i = 1; i < TT; ++i) {
        M[i][i] = w[0];
        M[i][0] -= w[i - 1];
        for (int k = 1; k < i; ++k)
            M[i][k] = -(w[i - k - 1] - w[i - k]);
    }
    double pref = pow(0.1, -0.5) / 0.886226925452758;
    MMat r;
    for (int i = 0; i < TT; ++i)
        for (int j = 0; j < TT; ++j)
            r.m[i][j] = (float)(pref * M[i][j]);
    return r;
}

extern "C" void kernel_launch(void* const* d_in, const int* in_sizes, int n_in,
                              void* d_out, int out_size, void* d_ws, size_t ws_size,
                              hipStream_t stream)
{
    const float* u  = (const float*)d_in[0];
    const float* f1 = (const float*)d_in[1];
    float* out = (float*)d_out;
    float* ws  = (float*)d_ws;

    MMat M = make_M();

    hipMemsetAsync(ws, 0, 2 * sizeof(float), stream);

    dim3 block(64, 4);
    dim3 grid(9, 256);   // 9 col-windows, 256*8 = 2048 rows (2 rows/thread)
    phy_kernel<<<grid, block, 0, stream>>>(u, f1, M, ws);

    bc_kernel<<<(10 * 2048 + 255) / 256, 256, 0, stream>>>(u, ws);

    fin_kernel<<<1, 1, 0, stream>>>(ws, out);
}